// Round 4
// baseline (1406.203 us; speedup 1.0000x reference)
//
#include <hip/hip_runtime.h>
#include <cmath>

struct K32 { float k[32]; };
struct K16 { float k[16]; };

#define THETA 10.0f

// ============ fused psp + conv(stride2,pad1) + spike ============
// block: 4 waves, tile = (n, csp, ho, group of TWB wo), COE = COUT/COSPLIT.
// Per input channel c: stage raw spikes (float2, zero-filled pads) -> FIR in
// place (thread-per-row, register row) -> conv accumulate (lane = t, ds_read
// immediate offsets). Then spike along t and coalesced float2 store.
template <int CIN, int COUT, int KK, int WT, int COSPLIT>
__global__ __launch_bounds__(256)
void psc_kernel(const float* __restrict__ x, const float* __restrict__ w,
                float* __restrict__ s, int N, int Hin, int Win,
                int Hout, int Wout, K32 pk, K16 rk) {
  constexpr int TWB = 4 * WT;                 // wo per block
  constexpr int XR  = 2 * (WT - 1) + KK;      // cols per wave
  constexpr int XRB = 2 * (TWB - 1) + KK;     // cols per block
  constexpr int NR  = KK * XRB;               // patch rows per channel
  constexpr int COE = COUT / COSPLIT;         // co handled per block
  constexpr int SPR = COE * TWB;              // spike rows
  constexpr int LDSF = (NR * 51 > SPR * 51) ? NR * 51 : SPR * 51;
  __shared__ float lds[LDSF];

  const int tid = threadIdx.x;
  const int wave = tid >> 6;
  const int lane = tid & 63;
  const int tt = lane < 50 ? lane : 49;

  const int groups = (Wout + TWB - 1) / TWB;
  int b = blockIdx.x;
  const int group = b % groups; b /= groups;
  const int ho = b % Hout; b /= Hout;
  const int csp = b % COSPLIT;
  const int n = b / COSPLIT;

  const int wi0 = 2 * group * TWB - 1;        // patch col 0 -> this wi

  float acc[COE][WT] = {};

#pragma unroll 1
  for (int c = 0; c < CIN; ++c) {
    // ---- stage channel c (float2 global, 2x b32 LDS, zero-fill pads) ----
    const float* xc = x + (size_t)(n * CIN + c) * Hin * Win * 50;
    for (int u = tid; u < NR * 25; u += 256) {
      const int rr = u / 25;
      const int j = u - rr * 25;
      const int kh = rr / XRB;
      const int wic = rr - kh * XRB;
      const int hi = 2 * ho + kh - 1;
      const int wi = wi0 + wic;
      float2 v = make_float2(0.f, 0.f);
      if ((unsigned)hi < (unsigned)Hin && (unsigned)wi < (unsigned)Win)
        v = *(const float2*)(xc + ((size_t)hi * Win + wi) * 50 + 2 * j);
      lds[rr * 51 + 2 * j] = v.x;
      lds[rr * 51 + 2 * j + 1] = v.y;
    }
    __syncthreads();
    // ---- FIR (psp) in place: thread-per-row, row cached in registers ----
    if (tid < NR) {
      float xr_[50];
#pragma unroll
      for (int t = 0; t < 50; ++t) xr_[t] = lds[tid * 51 + t];
#pragma unroll
      for (int t = 0; t < 50; ++t) {
        float a = 0.f;
#pragma unroll
        for (int k = 31; k >= 0; --k)          // x-index ascending (oldest first)
          if (t - k >= 0) a += xr_[t - k] * pk.k[k];
        lds[tid * 51 + t] = a;
      }
    }
    __syncthreads();
    // ---- conv accumulate from LDS (lane = t) ----
    const int colb = 2 * wave * WT;
#pragma unroll
    for (int kh = 0; kh < KK; ++kh) {
      float xr[XR];
#pragma unroll
      for (int i = 0; i < XR; ++i) xr[i] = lds[(kh * XRB + colb + i) * 51 + tt];
#pragma unroll
      for (int co = 0; co < COE; ++co)
#pragma unroll
        for (int kw = 0; kw < KK; ++kw) {
          const float wv = w[(((csp * COE + co) * CIN + c) * KK + kh) * KK + kw];
#pragma unroll
          for (int wl = 0; wl < WT; ++wl)
            acc[co][wl] += xr[2 * wl + kw] * wv;
        }
    }
    __syncthreads();   // before next channel's staging overwrites the patch
  }

  // ---- transpose acc into LDS spike region ----
  if (lane < 50) {
#pragma unroll
    for (int co = 0; co < COE; ++co)
#pragma unroll
      for (int wl = 0; wl < WT; ++wl)
        lds[(co * TWB + wave * WT + wl) * 51 + lane] = acc[co][wl];
  }
  __syncthreads();
  // ---- spike along t, one thread per output row, in place ----
  if (tid < SPR) {
    const int wol = tid % TWB;
    if (group * TWB + wol < Wout) {
      float buf[16];
#pragma unroll
      for (int j = 0; j < 16; ++j) buf[j] = 0.f;
#pragma unroll
      for (int t = 0; t < 50; ++t) {
        float v = lds[tid * 51 + t] + buf[t & 15];
        buf[t & 15] = 0.f;
        float sp = 0.f;
        if (v >= THETA) {
          sp = 1.f;
#pragma unroll
          for (int j = 0; j < 16; ++j) buf[(t + 1 + j) & 15] += rk.k[j];
        }
        lds[tid * 51 + t] = sp;
      }
    }
  }
  __syncthreads();
  // ---- store (float2 fast path when the group is full-width) ----
  const int nv = min(TWB, Wout - group * TWB);
  if (nv == TWB) {
    constexpr int PER2 = TWB * 25;
    for (int i2 = tid; i2 < COE * PER2; i2 += 256) {
      const int co = i2 / PER2;
      const int r2 = i2 - co * PER2;
      const int wol = r2 / 25;
      const int j = r2 - wol * 25;
      float2 v;
      v.x = lds[(co * TWB + wol) * 51 + 2 * j];
      v.y = lds[(co * TWB + wol) * 51 + 2 * j + 1];
      *(float2*)(s + (((size_t)(n * COUT + csp * COE + co) * Hout + ho) * Wout
                      + group * TWB) * 50 + 2 * r2) = v;
    }
  } else {
    for (int co = 0; co < COE; ++co) {
      float* ob = s + (((size_t)(n * COUT + csp * COE + co) * Hout + ho) * Wout
                       + group * TWB) * 50;
      for (int j = tid; j < nv * 50; j += 256) {
        const int wol = j / 50;
        ob[j] = lds[(co * TWB + wol) * 51 + (j - wol * 50)];
      }
    }
  }
}

// ============ fused psp -> 2x2 sum-pool * 2.75 -> spike ============
__global__ __launch_bounds__(256)
void pps_kernel(const float* __restrict__ in, float* __restrict__ out,
                int Hin, int Win, int Hout, int Wout, int nseg,
                K32 pk, K16 rk) {
  __shared__ float lds[128 * 51];
  const int tid = threadIdx.x;
  const int seg = blockIdx.x % nseg;
  const int rest = blockIdx.x / nseg;
  const int ho = rest % Hout;
  const int nc = rest / Hout;
  const int wbase = seg * 64;
  const int nw = min(64, 2 * Wout - wbase);
  const int nwo = nw >> 1;
  const float* base = in + ((size_t)(nc * Hin + 2 * ho) * Win + wbase) * 50;
  // float2 staging
  for (int u = tid; u < 2 * nw * 25; u += 256) {
    const int r = u / 25;
    const int j = u - r * 25;
    const int h = r >= nw ? 1 : 0;
    const int wl = r - h * nw;
    const float2 v = *(const float2*)(base + ((size_t)h * Win + wl) * 50 + 2 * j);
    lds[r * 51 + 2 * j] = v.x;
    lds[r * 51 + 2 * j + 1] = v.y;
  }
  __syncthreads();
  // FIR split across 2 threads/row, constant-bound register snapshots
  const int r = tid & 127;
  const int part = tid >> 7;
  const bool act = r < 2 * nw;
  float x[50];
  if (act) {
    if (part == 0) {
#pragma unroll
      for (int t = 0; t < 25; ++t) x[t] = lds[r * 51 + t];
    } else {
#pragma unroll
      for (int t = 0; t < 50; ++t) x[t] = lds[r * 51 + t];
    }
  }
  __syncthreads();
  if (act) {
    if (part == 0) {
#pragma unroll
      for (int t = 0; t < 25; ++t) {
        float a = 0.f;
#pragma unroll
        for (int k = 31; k >= 0; --k)
          if (t - k >= 0) a += x[t - k] * pk.k[k];
        lds[r * 51 + t] = a;
      }
    } else {
#pragma unroll
      for (int t = 25; t < 50; ++t) {
        float a = 0.f;
#pragma unroll
        for (int k = 31; k >= 0; --k)
          if (t - k >= 0) a += x[t - k] * pk.k[k];
        lds[r * 51 + t] = a;
      }
    }
  }
  __syncthreads();
  // pool ((h0w0+h0w1)+h1w0)+h1w1 then spike; write in place into row 2*tid
  if (tid < nwo) {
    float buf[16];
#pragma unroll
    for (int j = 0; j < 16; ++j) buf[j] = 0.f;
    const int r00 = (2 * tid) * 51, r01 = (2 * tid + 1) * 51;
    const int r10 = (nw + 2 * tid) * 51, r11 = (nw + 2 * tid + 1) * 51;
#pragma unroll
    for (int t = 0; t < 50; ++t) {
      const float u0 = (((lds[r00 + t] + lds[r01 + t]) + lds[r10 + t]) + lds[r11 + t]) * 2.75f;
      float v = u0 + buf[t & 15];
      buf[t & 15] = 0.f;
      float sp = 0.f;
      if (v >= THETA) {
        sp = 1.f;
#pragma unroll
        for (int j = 0; j < 16; ++j) buf[(t + 1 + j) & 15] += rk.k[j];
      }
      lds[r00 + t] = sp;
    }
  }
  __syncthreads();
  float* ob = out + ((size_t)(nc * Hout + ho) * Wout + seg * 32) * 50;
  for (int i2 = tid; i2 < nwo * 25; i2 += 256) {
    const int wo = i2 / 25;
    const int j = i2 - wo * 25;
    float2 v;
    v.x = lds[(2 * wo) * 51 + 2 * j];
    v.y = lds[(2 * wo) * 51 + 2 * j + 1];
    *(float2*)(ob + 2 * i2) = v;
  }
}

// ============ psp: thread-per-row, registers only, float2 I/O ============
__global__ __launch_bounds__(256)
void psp_kernel(const float* __restrict__ in, float* __restrict__ out,
                int nrows, K32 pk) {
  const int r = blockIdx.x * 256 + threadIdx.x;
  if (r >= nrows) return;
  const float2* ip = (const float2*)(in + (size_t)r * 50);
  float x[50];
#pragma unroll
  for (int i = 0; i < 25; ++i) {
    const float2 v = ip[i];
    x[2 * i] = v.x;
    x[2 * i + 1] = v.y;
  }
  float2* op = (float2*)(out + (size_t)r * 50);
#pragma unroll
  for (int i = 0; i < 25; ++i) {
    float2 yv;
    {
      const int t = 2 * i;
      float a = 0.f;
#pragma unroll
      for (int k = 31; k >= 0; --k)
        if (t - k >= 0) a += x[t - k] * pk.k[k];
      yv.x = a;
    }
    {
      const int t = 2 * i + 1;
      float a = 0.f;
#pragma unroll
      for (int k = 31; k >= 0; --k)
        if (t - k >= 0) a += x[t - k] * pk.k[k];
      yv.y = a;
    }
    op[i] = yv;
  }
}

// ============ fc + final spike ============
__global__ __launch_bounds__(512)
void fc_spike_kernel(const float* __restrict__ w, const float* __restrict__ u,
                     float* __restrict__ out, K16 rk) {
  __shared__ float lds[8 * 51];
  const int tid = threadIdx.x;
  const int wave = tid >> 6, lane = tid & 63;
  const int o = wave & 1, n = wave >> 1;
  const int tt = lane < 50 ? lane : 49;
  const float* wrow = w + (size_t)o * 2048;
  const float* ub = u + (size_t)n * 2048 * 50;
  float acc = 0.f;
#pragma unroll 16
  for (int i = 0; i < 2048; ++i) acc += wrow[i] * ub[(size_t)i * 50 + tt];
  if (lane < 50) lds[wave * 51 + lane] = acc;
  __syncthreads();
  if (tid < 8) {
    float buf[16];
#pragma unroll
    for (int j = 0; j < 16; ++j) buf[j] = 0.f;
#pragma unroll
    for (int t = 0; t < 50; ++t) {
      float v = lds[tid * 51 + t] + buf[t & 15];
      buf[t & 15] = 0.f;
      float sp = 0.f;
      if (v >= THETA) {
        sp = 1.f;
#pragma unroll
        for (int j = 0; j < 16; ++j) buf[(t + 1 + j) & 15] += rk.k[j];
      }
      out[tid * 50 + t] = sp;
    }
  }
}

extern "C" void kernel_launch(void* const* d_in, const int* in_sizes, int n_in,
                              void* d_out, int out_size, void* d_ws, size_t ws_size,
                              hipStream_t stream) {
  const float* xin = (const float*)d_in[0];  // [4,2,256,256,50] binary spikes
  const float* w1  = (const float*)d_in[1];  // [8,2,5,5]
  const float* w2  = (const float*)d_in[2];  // [16,8,3,3]
  const float* w3  = (const float*)d_in[3];  // [32,16,3,3]
  const float* wfc = (const float*)d_in[4];  // [2,32,8,8]
  float* out = (float*)d_out;                // [4,2,1,1,50]

  float* R0 = (float*)d_ws;                  // 26,214,400 floats
  float* R1 = R0 + 26214400;

  K32 pk;
  for (int k = 0; k < 32; ++k)
    pk.k[k] = (float)(((double)k / 10.0) * exp(1.0 - (double)k / 10.0));
  K16 rk;
  for (int j = 0; j < 16; ++j) {
    const double tr = (double)(j + 1);
    rk.k[j] = (float)(-2.0 * 10.0 * tr * exp(1.0 - tr));
  }

  // 1. psp1+conv1+spike1: xin -> R1 = s1 [4,8,127,127,50]
  //    TWB=16, groups=8, grid = 8*127*1*4
  psc_kernel<2, 8, 5, 4, 1><<<8 * 127 * 4, 256, 0, stream>>>(
      xin, w1, R1, 4, 256, 256, 127, 127, pk, rk);
  // 2. psp2+pool1+spike2: R1 -> R0 = s2 [4,8,63,63,50]
  pps_kernel<<<4 * 8 * 63 * 2, 256, 0, stream>>>(R1, R0, 127, 127, 63, 63, 2, pk, rk);
  // 3. psp3+conv2+spike3: R0 -> R1 = s3 [4,16,32,32,50]
  //    TWB=16, groups=2, grid = 2*32*1*4
  psc_kernel<8, 16, 3, 4, 1><<<2 * 32 * 4, 256, 0, stream>>>(
      R0, w2, R1, 4, 63, 63, 32, 32, pk, rk);
  // 4. psp4+pool2+spike4: R1 -> R0 = s4 [4,16,16,16,50]
  pps_kernel<<<4 * 16 * 16, 256, 0, stream>>>(R1, R0, 32, 32, 16, 16, 1, pk, rk);
  // 5. psp5+conv3+spike5: R0 -> R1 = s5 [4,32,8,8,50]
  //    TWB=8, groups=1, COSPLIT=2, grid = 1*8*2*4
  psc_kernel<16, 32, 3, 2, 2><<<8 * 2 * 4, 256, 0, stream>>>(
      R0, w3, R1, 4, 16, 16, 8, 8, pk, rk);
  // 6. psp6: R1 -> R0 (8192 rows)
  psp_kernel<<<32, 256, 0, stream>>>(R1, R0, 8192, pk);
  // 7. fc + final spike -> out
  fc_spike_kernel<<<1, 512, 0, stream>>>(wfc, R0, out, rk);
}

// Round 5
// 610.835 us; speedup vs baseline: 2.3021x; 2.3021x over previous
//
#include <hip/hip_runtime.h>
#include <cmath>

struct K32 { float k[32]; };
struct K16 { float k[16]; };

#define THETA 10.0f

// ---------------- psp: thread-per-row, registers only, float2 I/O ----------------
__global__ __launch_bounds__(256)
void psp_kernel(const float* __restrict__ in, float* __restrict__ out,
                int nrows, K32 pk) {
  const int r = blockIdx.x * 256 + threadIdx.x;
  if (r >= nrows) return;
  const float2* ip = (const float2*)(in + (size_t)r * 50);
  float x[50];
#pragma unroll
  for (int i = 0; i < 25; ++i) {
    const float2 v = ip[i];
    x[2 * i] = v.x;
    x[2 * i + 1] = v.y;
  }
  float2* op = (float2*)(out + (size_t)r * 50);
#pragma unroll
  for (int i = 0; i < 25; ++i) {
    float2 yv;
    {
      const int t = 2 * i;
      float a = 0.f;
#pragma unroll
      for (int k = 31; k >= 0; --k)          // x-index ascending (oldest first)
        if (t - k >= 0) a += x[t - k] * pk.k[k];
      yv.x = a;
    }
    {
      const int t = 2 * i + 1;
      float a = 0.f;
#pragma unroll
      for (int k = 31; k >= 0; --k)
        if (t - k >= 0) a += x[t - k] * pk.k[k];
      yv.y = a;
    }
    op[i] = yv;
  }
}

// ---------------- fused conv (stride2,pad1) + spike ----------------
// wave=(n,ho,wo-tile), lane=t. Interior blocks (no pad taps) use a single
// base pointer per (c,kh) with immediate-offset loads (no bounds checks);
// boundary blocks use the checked path. Same term set & order -> bitwise equal.
template <int CIN, int COUT, int KK, int WT>
__global__ __launch_bounds__(256)
void conv_spike_kernel(const float* __restrict__ x, const float* __restrict__ w,
                       float* __restrict__ s, int N, int Hin, int Win,
                       int Hout, int Wout, K16 rk) {
  constexpr int XR = 2 * (WT - 1) + KK;
  constexpr int TW = 4 * WT;                 // wo span per block (4 waves)
  __shared__ float lds[COUT * TW * 51];      // 26 KB
  const int tid = threadIdx.x;
  const int wave = tid >> 6;
  const int lane = tid & 63;
  const int groups = (Wout + TW - 1) / TW;
  const int group = blockIdx.x % groups;
  const int rest = blockIdx.x / groups;
  const int ho = rest % Hout;
  const int n = rest / Hout;
  const int wo0 = group * TW + wave * WT;
  const int tt = lane < 50 ? lane : 49;

  const int hiMin = 2 * ho - 1;
  const int hiMax = 2 * ho + KK - 2;
  const int wiMin = 2 * (group * TW) - 1;
  const int wiMax = 2 * (group * TW + 3 * WT) - 1 + (XR - 1);
  const bool interior = (hiMin >= 0) && (hiMax < Hin) && (wiMin >= 0) && (wiMax < Win);

  float acc[COUT][WT] = {};
  if (interior) {
    for (int c = 0; c < CIN; ++c) {
#pragma unroll
      for (int kh = 0; kh < KK; ++kh) {
        const int hi = 2 * ho + kh - 1;
        const float* xp = x + (((size_t)(n * CIN + c) * Hin + hi) * Win + (2 * wo0 - 1)) * 50 + tt;
        float xr[XR];
#pragma unroll
        for (int i = 0; i < XR; ++i) xr[i] = xp[i * 50];
#pragma unroll
        for (int co = 0; co < COUT; ++co)
#pragma unroll
          for (int kw = 0; kw < KK; ++kw) {
            const float wv = w[((co * CIN + c) * KK + kh) * KK + kw];
#pragma unroll
            for (int wl = 0; wl < WT; ++wl)
              acc[co][wl] += xr[2 * wl + kw] * wv;
          }
      }
    }
  } else {
    for (int c = 0; c < CIN; ++c) {
#pragma unroll
      for (int kh = 0; kh < KK; ++kh) {
        const int hi = 2 * ho + kh - 1;
        if ((unsigned)hi >= (unsigned)Hin) continue;   // zero padding
        float xr[XR];
#pragma unroll
        for (int i = 0; i < XR; ++i) {
          const int wi = 2 * wo0 - 1 + i;
          xr[i] = ((unsigned)wi < (unsigned)Win)
                      ? x[(((size_t)(n * CIN + c) * Hin + hi) * Win + wi) * 50 + tt]
                      : 0.f;
        }
#pragma unroll
        for (int co = 0; co < COUT; ++co)
#pragma unroll
          for (int kw = 0; kw < KK; ++kw) {
            const float wv = w[((co * CIN + c) * KK + kh) * KK + kw];
#pragma unroll
            for (int wl = 0; wl < WT; ++wl)
              acc[co][wl] += xr[2 * wl + kw] * wv;
          }
      }
    }
  }

  if (lane < 50) {
#pragma unroll
    for (int co = 0; co < COUT; ++co)
#pragma unroll
      for (int wl = 0; wl < WT; ++wl)
        lds[(co * TW + wave * WT + wl) * 51 + lane] = acc[co][wl];
  }
  __syncthreads();
  // spike along t, one thread per output row, in place
  if (tid < COUT * TW) {
    const int wol = tid % TW;
    if (group * TW + wol < Wout) {
      float buf[16];
#pragma unroll
      for (int j = 0; j < 16; ++j) buf[j] = 0.f;
#pragma unroll
      for (int t = 0; t < 50; ++t) {
        float v = lds[tid * 51 + t] + buf[t & 15];
        buf[t & 15] = 0.f;
        float sp = 0.f;
        if (v >= THETA) {
          sp = 1.f;
#pragma unroll
          for (int j = 0; j < 16; ++j) buf[(t + 1 + j) & 15] += rk.k[j];
        }
        lds[tid * 51 + t] = sp;
      }
    }
  }
  __syncthreads();
  // store: float2 fast path when the group is full-width
  const int nv = min(TW, Wout - group * TW);
  if (nv == TW) {
    constexpr int PER2 = TW * 25;
    for (int i2 = tid; i2 < COUT * PER2; i2 += 256) {
      const int co = i2 / PER2;
      const int r2 = i2 - co * PER2;
      const int wol = r2 / 25;
      const int j = r2 - wol * 25;
      float2 v;
      v.x = lds[(co * TW + wol) * 51 + 2 * j];
      v.y = lds[(co * TW + wol) * 51 + 2 * j + 1];
      *(float2*)(s + (((size_t)(n * COUT + co) * Hout + ho) * Wout + group * TW) * 50 + 2 * r2) = v;
    }
  } else {
    const int per = nv * 50;
    for (int i = tid; i < COUT * per; i += 256) {
      const int co = i / per;
      const int j = i - co * per;
      const int wol = j / 50;
      const int t = j - wol * 50;
      s[(((size_t)(n * COUT + co) * Hout + ho) * Wout + group * TW) * 50 + j] =
          lds[(co * TW + wol) * 51 + t];
    }
  }
}

// ---------------- fused psp -> 2x2 sum-pool * 2.75 -> spike ----------------
__global__ __launch_bounds__(256)
void pps_kernel(const float* __restrict__ in, float* __restrict__ out,
                int Hin, int Win, int Hout, int Wout, int nseg,
                K32 pk, K16 rk) {
  __shared__ float lds[128 * 51];
  const int tid = threadIdx.x;
  const int seg = blockIdx.x % nseg;
  const int rest = blockIdx.x / nseg;
  const int ho = rest % Hout;
  const int nc = rest / Hout;
  const int wbase = seg * 64;
  const int nw = min(64, 2 * Wout - wbase);
  const int nwo = nw >> 1;
  const float* base = in + ((size_t)(nc * Hin + 2 * ho) * Win + wbase) * 50;
  // float2 staging
  for (int u = tid; u < 2 * nw * 25; u += 256) {
    const int r = u / 25;
    const int j = u - r * 25;
    const int h = r >= nw ? 1 : 0;
    const int wl = r - h * nw;
    const float2 v = *(const float2*)(base + ((size_t)h * Win + wl) * 50 + 2 * j);
    lds[r * 51 + 2 * j] = v.x;
    lds[r * 51 + 2 * j + 1] = v.y;
  }
  __syncthreads();
  // FIR split across 2 threads/row, constant-bound register snapshots
  const int r = tid & 127;
  const int part = tid >> 7;
  const bool act = r < 2 * nw;
  float x[50];
  if (act) {
    if (part == 0) {
#pragma unroll
      for (int t = 0; t < 25; ++t) x[t] = lds[r * 51 + t];
    } else {
#pragma unroll
      for (int t = 0; t < 50; ++t) x[t] = lds[r * 51 + t];
    }
  }
  __syncthreads();
  if (act) {
    if (part == 0) {
#pragma unroll
      for (int t = 0; t < 25; ++t) {
        float a = 0.f;
#pragma unroll
        for (int k = 31; k >= 0; --k)
          if (t - k >= 0) a += x[t - k] * pk.k[k];
        lds[r * 51 + t] = a;
      }
    } else {
#pragma unroll
      for (int t = 25; t < 50; ++t) {
        float a = 0.f;
#pragma unroll
        for (int k = 31; k >= 0; --k)
          if (t - k >= 0) a += x[t - k] * pk.k[k];
        lds[r * 51 + t] = a;
      }
    }
  }
  __syncthreads();
  // pool ((h0w0+h0w1)+h1w0)+h1w1 then spike; write in place into row 2*tid
  if (tid < nwo) {
    float buf[16];
#pragma unroll
    for (int j = 0; j < 16; ++j) buf[j] = 0.f;
    const int r00 = (2 * tid) * 51, r01 = (2 * tid + 1) * 51;
    const int r10 = (nw + 2 * tid) * 51, r11 = (nw + 2 * tid + 1) * 51;
#pragma unroll
    for (int t = 0; t < 50; ++t) {
      const float u0 = (((lds[r00 + t] + lds[r01 + t]) + lds[r10 + t]) + lds[r11 + t]) * 2.75f;
      float v = u0 + buf[t & 15];
      buf[t & 15] = 0.f;
      float sp = 0.f;
      if (v >= THETA) {
        sp = 1.f;
#pragma unroll
        for (int j = 0; j < 16; ++j) buf[(t + 1 + j) & 15] += rk.k[j];
      }
      lds[r00 + t] = sp;
    }
  }
  __syncthreads();
  float* ob = out + ((size_t)(nc * Hout + ho) * Wout + seg * 32) * 50;
  for (int i2 = tid; i2 < nwo * 25; i2 += 256) {
    const int wo = i2 / 25;
    const int j = i2 - wo * 25;
    float2 v;
    v.x = lds[(2 * wo) * 51 + 2 * j];
    v.y = lds[(2 * wo) * 51 + 2 * j + 1];
    *(float2*)(ob + 2 * i2) = v;
  }
}

// ---------------- fused fc + final spike: wave per (n,o), lane = t ----------------
__global__ __launch_bounds__(512)
void fc_spike_kernel(const float* __restrict__ w, const float* __restrict__ u,
                     float* __restrict__ out, K16 rk) {
  __shared__ float lds[8 * 51];
  const int tid = threadIdx.x;
  const int wave = tid >> 6, lane = tid & 63;
  const int o = wave & 1, n = wave >> 1;
  const int tt = lane < 50 ? lane : 49;
  const float* wrow = w + (size_t)o * 2048;
  const float* ub = u + (size_t)n * 2048 * 50;
  float acc = 0.f;
#pragma unroll 32
  for (int i = 0; i < 2048; ++i) acc += wrow[i] * ub[(size_t)i * 50 + tt];
  if (lane < 50) lds[wave * 51 + lane] = acc;
  __syncthreads();
  if (tid < 8) {
    float buf[16];
#pragma unroll
    for (int j = 0; j < 16; ++j) buf[j] = 0.f;
#pragma unroll
    for (int t = 0; t < 50; ++t) {
      float v = lds[tid * 51 + t] + buf[t & 15];
      buf[t & 15] = 0.f;
      float sp = 0.f;
      if (v >= THETA) {
        sp = 1.f;
#pragma unroll
        for (int j = 0; j < 16; ++j) buf[(t + 1 + j) & 15] += rk.k[j];
      }
      out[tid * 50 + t] = sp;
    }
  }
}

extern "C" void kernel_launch(void* const* d_in, const int* in_sizes, int n_in,
                              void* d_out, int out_size, void* d_ws, size_t ws_size,
                              hipStream_t stream) {
  const float* xin = (const float*)d_in[0];  // [4,2,256,256,50]
  const float* w1  = (const float*)d_in[1];  // [8,2,5,5]
  const float* w2  = (const float*)d_in[2];  // [16,8,3,3]
  const float* w3  = (const float*)d_in[3];  // [32,16,3,3]
  const float* wfc = (const float*)d_in[4];  // [2,32,8,8]
  float* out = (float*)d_out;                // [4,2,1,1,50]

  float* R0 = (float*)d_ws;                  // 26,214,400 floats
  float* R1 = R0 + 26214400;

  K32 pk;
  for (int k = 0; k < 32; ++k)
    pk.k[k] = (float)(((double)k / 10.0) * exp(1.0 - (double)k / 10.0));
  K16 rk;
  for (int j = 0; j < 16; ++j) {
    const double tr = (double)(j + 1);
    rk.k[j] = (float)(-2.0 * 10.0 * tr * exp(1.0 - tr));
  }

  // 1. psp1: input -> R0 (524288 rows)
  psp_kernel<<<2048, 256, 0, stream>>>(xin, R0, 524288, pk);
  // 2. conv1+spike1: R0 -> R1 = s1 [4,8,127,127,50]
  conv_spike_kernel<2, 8, 5, 4><<<4 * 127 * 8, 256, 0, stream>>>(R0, w1, R1, 4, 256, 256, 127, 127, rk);
  // 3. psp+pool+spike: R1 -> R0 = s2 [4,8,63,63,50]
  pps_kernel<<<4 * 8 * 63 * 2, 256, 0, stream>>>(R1, R0, 127, 127, 63, 63, 2, pk, rk);
  // 4. psp3: R0 -> R1 (127008 rows)
  psp_kernel<<<497, 256, 0, stream>>>(R0, R1, 127008, pk);
  // 5. conv2+spike3: R1 -> R0 = s3 [4,16,32,32,50]
  conv_spike_kernel<8, 16, 3, 2><<<4 * 32 * 4, 256, 0, stream>>>(R1, w2, R0, 4, 63, 63, 32, 32, rk);
  // 6. psp+pool+spike: R0 -> R1 = s4 [4,16,16,16,50]
  pps_kernel<<<4 * 16 * 16, 256, 0, stream>>>(R0, R1, 32, 32, 16, 16, 1, pk, rk);
  // 7. psp5: R1 -> R0 (16384 rows)
  psp_kernel<<<64, 256, 0, stream>>>(R1, R0, 16384, pk);
  // 8. conv3+spike5: R0 -> R1 = s5 [4,32,8,8,50]
  conv_spike_kernel<16, 32, 3, 1><<<4 * 8 * 2, 256, 0, stream>>>(R0, w3, R1, 4, 16, 16, 8, 8, rk);
  // 9. psp6: R1 -> R0 (8192 rows)
  psp_kernel<<<32, 256, 0, stream>>>(R1, R0, 8192, pk);
  // 10. fc + final spike -> out
  fc_spike_kernel<<<1, 512, 0, stream>>>(wfc, R0, out, rk);
}